// Round 15
// baseline (734.234 us; speedup 1.0000x reference)
//
#include <hip/hip_runtime.h>
#include <hip/hip_bf16.h>

#define NN 50000
#define NR 8
#define DIM 128
#define NE 800000
#define TM 32     // targets per block
#define PAD 136   // A-tile row stride in bf16 (128 + 8): 2-way LDS conflicts only (free)
#define NB 1563   // ceil(NN/TM)

using floatx4 = __attribute__((ext_vector_type(4))) float;
using bf16x8  = __attribute__((ext_vector_type(8))) __bf16;

// ---------------- workspace layout (in floats) ----------------
// zeroed region: [0, 801152) = cnt + wsum + S2X1
#define OFF_CNT   0u         // 400000: int counts -> float inv in place (seg = t*8+r)
#define OFF_WSUM  400000u    // 400000: wsum[r*NN+h] fp32 atomic accum
#define OFF_S2    800000u    // 1024 S2 + 128 X1 (atomic finish by s2red_k)
#define OFF_OFFS  801152u    // 400000 ints: CSR offsets (end-offsets after fillw)
#define OFF_PART  1201152u   // 512 ints: scan partials
#define OFF_EH    1201664u   // 800000 ints: CSR-sorted edge head indices
#define OFF_XB    2001664u   // 6.4M bf16: x_emb in bf16
#define OFF_WF    5201664u   // 9*2048*8 bf16: weights in MFMA frag order
#define OFF_S2P   5275392u   // NB*1152: per-block S2/X1 partials

// ---------------- merged prep: bf16 cast + weight frags + (t,rel) counts ----------------
__global__ __launch_bounds__(256) void prep_k(
    const float* __restrict__ x, __bf16* __restrict__ xb,
    const float* __restrict__ W1, const float* __restrict__ root1, __bf16* __restrict__ wf,
    const int* __restrict__ r, const int* __restrict__ t, int* __restrict__ cnt)
{
    const int gid = blockIdx.x * 256 + threadIdx.x;
    const int nthr = gridDim.x * 256;

    if (gid < 9 * 2048) {
        int mat = gid >> 11, idx = gid & 2047;
        const float* B = (mat < 8) ? (W1 + (size_t)mat * DIM * DIM) : root1;
        int lt = idx & 63, fid = idx >> 6;
        int s = fid >> 3, nt = fid & 7;
        int n = nt * 16 + (lt & 15);
        int kb = s * 32 + (lt >> 4) * 8;
        bf16x8 v;
#pragma unroll
        for (int j = 0; j < 8; ++j) v[j] = (__bf16)B[(kb + j) * DIM + n];
        *reinterpret_cast<bf16x8*>(wf + ((size_t)mat * 2048 + idx) * 8) = v;
    }
    for (int i = gid; i < NN * DIM / 4; i += nthr) {
        int base = i * 4;
        float4 v = *reinterpret_cast<const float4*>(x + base);
        __bf16 o[4] = {(__bf16)v.x, (__bf16)v.y, (__bf16)v.z, (__bf16)v.w};
        *reinterpret_cast<uint2*>(xb + base) = *reinterpret_cast<uint2*>(o);
    }
    for (int i = gid; i < NE / 4; i += nthr) {
        int base = i * 4;
        int4 rv = *reinterpret_cast<const int4*>(r + base);
        int4 tv = *reinterpret_cast<const int4*>(t + base);
        atomicAdd(&cnt[tv.x * NR + rv.x], 1);
        atomicAdd(&cnt[tv.y * NR + rv.y], 1);
        atomicAdd(&cnt[tv.z * NR + rv.z], 1);
        atomicAdd(&cnt[tv.w * NR + rv.w], 1);
    }
}

// ---------------- 3-pass exclusive scan (R10/R14 proven) ----------------
__global__ __launch_bounds__(256) void scanA_k(const int* cnt, float* invout,
                                               int* __restrict__ offs, int* __restrict__ part) {
    __shared__ int lds[256];
    const int tid = threadIdx.x;
    const int base = blockIdx.x * 1024 + tid * 4;
    int v[4] = {0, 0, 0, 0};
    if (base + 3 < NR * NN) {
        int4 q = *reinterpret_cast<const int4*>(cnt + base);
        v[0] = q.x; v[1] = q.y; v[2] = q.z; v[3] = q.w;
    } else {
#pragma unroll
        for (int j = 0; j < 4; ++j) if (base + j < NR * NN) v[j] = cnt[base + j];
    }
    int tsum = v[0] + v[1] + v[2] + v[3];
    lds[tid] = tsum;
    __syncthreads();
#pragma unroll
    for (int off = 1; off < 256; off <<= 1) {
        int val = (tid >= off) ? lds[tid - off] : 0;
        __syncthreads();
        if (tid >= off) lds[tid] += val;
        __syncthreads();
    }
    int run = lds[tid] - tsum;
#pragma unroll
    for (int j = 0; j < 4; ++j) {
        if (base + j < NR * NN) {
            offs[base + j] = run;
            invout[base + j] = 1.0f / (float)(v[j] > 1 ? v[j] : 1);
        }
        run += v[j];
    }
    if (tid == 255) part[blockIdx.x] = lds[255];
}

__global__ __launch_bounds__(512) void scanB_k(int* __restrict__ part) {
    __shared__ int lds[512];
    const int tid = threadIdx.x;
    int v = (tid < 391) ? part[tid] : 0;
    lds[tid] = v;
    __syncthreads();
#pragma unroll
    for (int off = 1; off < 512; off <<= 1) {
        int val = (tid >= off) ? lds[tid - off] : 0;
        __syncthreads();
        if (tid >= off) lds[tid] += val;
        __syncthreads();
    }
    part[tid] = lds[tid] - v;  // exclusive
}

__global__ __launch_bounds__(256) void scanC_k(int* __restrict__ offs, const int* __restrict__ part) {
    const int base = blockIdx.x * 1024 + threadIdx.x * 4;
    const int add = part[blockIdx.x];
#pragma unroll
    for (int j = 0; j < 4; ++j)
        if (base + j < NR * NN) offs[base + j] += add;
}

// ---------------- merged CSR fill + wsum, 4 edges/thread (R10/R14 proven) ----------------
__global__ void fillw_k(const int* __restrict__ h, const int* __restrict__ r, const int* __restrict__ t,
                        int* __restrict__ offs, int* __restrict__ eh,
                        const float* __restrict__ inv, float* __restrict__ wsum) {
    int base = (blockIdx.x * 256 + threadIdx.x) * 4;
    if (base + 3 < NE) {
        int4 hv = *reinterpret_cast<const int4*>(h + base);
        int4 rv = *reinterpret_cast<const int4*>(r + base);
        int4 tv = *reinterpret_cast<const int4*>(t + base);
        int g0 = tv.x * NR + rv.x, g1 = tv.y * NR + rv.y;
        int g2 = tv.z * NR + rv.z, g3 = tv.w * NR + rv.w;
        int p0 = atomicAdd(&offs[g0], 1);
        int p1 = atomicAdd(&offs[g1], 1);
        int p2 = atomicAdd(&offs[g2], 1);
        int p3 = atomicAdd(&offs[g3], 1);
        eh[p0] = hv.x; eh[p1] = hv.y; eh[p2] = hv.z; eh[p3] = hv.w;
        atomicAdd(&wsum[rv.x * NN + hv.x], inv[g0]);
        atomicAdd(&wsum[rv.y * NN + hv.y], inv[g1]);
        atomicAdd(&wsum[rv.z * NN + hv.z], inv[g2]);
        atomicAdd(&wsum[rv.w * NN + hv.w], inv[g3]);
    } else {
        for (int e = base; e < NE; ++e) {
            int he = h[e], re = r[e];
            int seg = t[e] * NR + re;
            int pos = atomicAdd(&offs[seg], 1);
            eh[pos] = he;
            atomicAdd(&wsum[re * NN + he], inv[seg]);
        }
    }
}

// ---------------- fused layer 1 + layer-2 partials: edge-balanced streaming gather ----------------
// Per term-pair tp: segments k = trow*2+u (u = term parity) get pair-local offsets pls[]
// (64-wide LDS scan). Each 16-lane slot takes an equal EDGE chunk and owns every segment
// that STARTS in its chunk (segmented-reduction carry rule -> no atomics, each segment
// flushed exactly once, incl. zero-length). Slot streams its contiguous pair-local range
// with a depth-4 register pipeline (independent eh->xb loads, no max-padding).
__global__ __launch_bounds__(256, 4) void rgcn_fused_k(
    const int* __restrict__ offs, const int* __restrict__ eh, const float* __restrict__ inv,
    const __bf16* __restrict__ xb, const __bf16* __restrict__ wf,
    const float* __restrict__ b1, const float* __restrict__ wsum,
    float* __restrict__ S2P)
{
    __shared__ __attribute__((aligned(16))) __bf16 Atile[2][TM * PAD];  // 17.4 KB (scan temp + red reuse)
    __shared__ int   loffs[TM * NR + 1];
    __shared__ float invl[TM * NR];
    __shared__ float wsl[NR][TM];
    __shared__ int   pls[4 * 65];   // per-tp pair-local segment starts + sentinel total
    const int tid = threadIdx.x;
    const int wave = tid >> 6, lane = tid & 63, quad = lane >> 4;
    const int slot = tid >> 4, sl = tid & 15;   // 16 gather slots x 16 lanes
    const int tbase = blockIdx.x * TM;
    const int segbase = tbase * NR;

    for (int j = tid; j < TM * NR + 1; j += 256) {
        int g = segbase + j - 1;
        loffs[j] = (g < 0) ? 0 : offs[g > NR * NN - 1 ? NR * NN - 1 : g];
    }
    for (int j = tid; j < TM * NR; j += 256) {
        int g = segbase + j;
        invl[j] = (g < NR * NN) ? inv[g] : 0.f;
    }
    if (tid < NR * TM) {
        int rr = tid >> 5, n = tbase + (tid & 31);
        wsl[rr][tid & 31] = (n < NN) ? wsum[rr * NN + n] : 0.f;
    }
    __syncthreads();

    // ---- build pls: 4 parallel 64-wide scans of segment lengths in (trow,u) order ----
    {
        int* ss = reinterpret_cast<int*>(&Atile[0][0]);
        const int tp = tid >> 6, k = tid & 63;          // k = trow*2 + u
        const int j = (k >> 1) * 8 + tp * 2 + (k & 1);
        const int slen = loffs[j + 1] - loffs[j];
        ss[tid] = slen;
        __syncthreads();
#pragma unroll
        for (int off = 1; off < 64; off <<= 1) {
            int v = (k >= off) ? ss[tid - off] : 0;
            __syncthreads();
            ss[tid] += v;
            __syncthreads();
        }
        pls[tp * 65 + k] = ss[tid] - slen;              // exclusive
        if (k == 63) pls[tp * 65 + 64] = ss[tid];       // sentinel = total
    }
    __syncthreads();

    floatx4 C[4];
#pragma unroll
    for (int i = 0; i < 4; ++i) C[i] = (floatx4)0.f;
    const int arow = (wave & 1) * 16 + (lane & 15);   // wave row-strip
    const int ntg0 = (wave >> 1) * 4;                 // wave col-strip (4 nt each)

    // ---- 4 term-pairs: balanced streaming gather + MFMA ----
    for (int tp = 0; tp < 4; ++tp) {
        const int b65 = tp * 65, tp2 = tp * 2;
        const int n = pls[b65 + 64];
        const int c0 = (slot * n) >> 4;
        const int c1 = (slot == 15) ? n + 1 : (((slot + 1) * n) >> 4);
        // first owned segment: first k with pls >= c0
        int lo = 0, hi = 64;
        while (lo < hi) { int mid = (lo + hi) >> 1; if (pls[b65 + mid] < c0) lo = mid + 1; else hi = mid; }
        const int i0 = lo;
        lo = i0; hi = 64;
        while (lo < hi) { int mid = (lo + hi) >> 1; if (pls[b65 + mid] < c1) lo = mid + 1; else hi = mid; }
        const int iend = lo;
        const int qs = pls[b65 + i0];
        const int qe = pls[b65 + (iend < 64 ? iend : 64)];  // iend==64 -> sentinel n

        float a[8] = {0.f, 0.f, 0.f, 0.f, 0.f, 0.f, 0.f, 0.f};
        bf16x8 y[4];
        int il = i0;
        // prime depth-4 pipeline
#pragma unroll
        for (int d = 0; d < 4; ++d) {
            int q = qs + d;
            if (q < qe) {
                while (pls[b65 + il + 1] <= q) ++il;
                int g = loffs[(il >> 1) * 8 + tp2 + (il & 1)] + (q - pls[b65 + il]);
                int he = eh[g];
                y[d] = *reinterpret_cast<const bf16x8*>(xb + (size_t)he * DIM + sl * 8);
            }
        }
        int ic = i0;
        for (int q = qs; q < qe; ++q) {
            // crossing: flush finished segments (incl. zero-length)
            while (pls[b65 + ic + 1] <= q) {
                float sc = invl[(ic >> 1) * 8 + tp2 + (ic & 1)];
                bf16x8 out;
#pragma unroll
                for (int k = 0; k < 8; ++k) { out[k] = (__bf16)(a[k] * sc); a[k] = 0.f; }
                *reinterpret_cast<bf16x8*>(&Atile[ic & 1][(ic >> 1) * PAD + sl * 8]) = out;
                ++ic;
            }
            int d = (q - qs) & 3;
#pragma unroll
            for (int k = 0; k < 8; ++k) a[k] += (float)y[d][k];
            int qn = q + 4;
            if (qn < qe) {
                while (pls[b65 + il + 1] <= qn) ++il;
                int g = loffs[(il >> 1) * 8 + tp2 + (il & 1)] + (qn - pls[b65 + il]);
                int he = eh[g];
                y[d] = *reinterpret_cast<const bf16x8*>(xb + (size_t)he * DIM + sl * 8);
            }
        }
        // flush remaining owned segments (last active + trailing zero-length)
        for (; ic < iend; ++ic) {
            float sc = invl[(ic >> 1) * 8 + tp2 + (ic & 1)];
            bf16x8 out;
#pragma unroll
            for (int k = 0; k < 8; ++k) { out[k] = (__bf16)(a[k] * sc); a[k] = 0.f; }
            *reinterpret_cast<bf16x8*>(&Atile[ic & 1][(ic >> 1) * PAD + sl * 8]) = out;
        }
        __syncthreads();

        // ---- MFMA: C += A_tile @ W_{2tp}, W_{2tp+1} ----
#pragma unroll
        for (int u = 0; u < 2; ++u) {
            const __bf16* wterm = wf + (size_t)(tp2 + u) * 2048 * 8;
#pragma unroll
            for (int s = 0; s < 4; ++s) {
                bf16x8 af = *reinterpret_cast<const bf16x8*>(&Atile[u][arow * PAD + s * 32 + quad * 8]);
#pragma unroll
                for (int nt = 0; nt < 4; ++nt) {
                    bf16x8 bf = *reinterpret_cast<const bf16x8*>(
                        wterm + (size_t)((s * 8 + ntg0 + nt) * 64 + lane) * 8);
                    C[nt] = __builtin_amdgcn_mfma_f32_16x16x32_bf16(af, bf, C[nt], 0, 0, 0);
                }
            }
        }
        __syncthreads();
    }

    // ---- root term: A row = xb[t] ----
#pragma unroll
    for (int i = 0; i < 2; ++i) {
        int trow = slot + i * 16;
        int t = tbase + trow;
        bf16x8 out;
        if (t < NN) {
            out = *reinterpret_cast<const bf16x8*>(xb + (size_t)t * DIM + sl * 8);
        } else {
#pragma unroll
            for (int j = 0; j < 8; ++j) out[j] = (__bf16)0.f;
        }
        *reinterpret_cast<bf16x8*>(&Atile[0][trow * PAD + sl * 8]) = out;
    }
    __syncthreads();
    {
        const __bf16* wterm = wf + (size_t)8 * 2048 * 8;
#pragma unroll
        for (int s = 0; s < 4; ++s) {
            bf16x8 af = *reinterpret_cast<const bf16x8*>(&Atile[0][arow * PAD + s * 32 + quad * 8]);
#pragma unroll
            for (int nt = 0; nt < 4; ++nt) {
                bf16x8 bf = *reinterpret_cast<const bf16x8*>(
                    wterm + (size_t)((s * 8 + ntg0 + nt) * 64 + lane) * 8);
                C[nt] = __builtin_amdgcn_mfma_f32_16x16x32_bf16(af, bf, C[nt], 0, 0, 0);
            }
        }
    }
    __syncthreads();   // Atile dead -> reuse as reduction scratch

    // ---- epilogue: bias + relu in-register, fused S2/X1 block partials ----
    float* red = reinterpret_cast<float*>(&Atile[0][0]);   // [4][576] = 9.2 KB
    const int rowl0 = (wave & 1) * 16 + quad * 4;
    const int colc = lane & 15;
#pragma unroll
    for (int nt = 0; nt < 4; ++nt) {
        float badd = b1[ntg0 * 16 + nt * 16 + colc];
#pragma unroll
        for (int i = 0; i < 4; ++i) C[nt][i] = fmaxf(C[nt][i] + badd, 0.f);
    }
    float rmask[4];
#pragma unroll
    for (int i = 0; i < 4; ++i) rmask[i] = (tbase + rowl0 + i < NN) ? 1.f : 0.f;
#pragma unroll
    for (int nt = 0; nt < 4; ++nt) {
        float p = rmask[0] * C[nt][0] + rmask[1] * C[nt][1] + rmask[2] * C[nt][2] + rmask[3] * C[nt][3];
        p += __shfl_xor(p, 16);
        p += __shfl_xor(p, 32);
        if (quad == 0) red[wave * 576 + nt * 16 + colc] = p;
    }
#pragma unroll
    for (int rr = 0; rr < NR; ++rr) {
        float w0 = wsl[rr][rowl0], w1 = wsl[rr][rowl0 + 1];
        float w2 = wsl[rr][rowl0 + 2], w3 = wsl[rr][rowl0 + 3];
#pragma unroll
        for (int nt = 0; nt < 4; ++nt) {
            float p = w0 * C[nt][0] + w1 * C[nt][1] + w2 * C[nt][2] + w3 * C[nt][3];
            p += __shfl_xor(p, 16);
            p += __shfl_xor(p, 32);
            if (quad == 0) red[wave * 576 + 64 + rr * 64 + nt * 16 + colc] = p;
        }
    }
    __syncthreads();
    for (int j = tid; j < 1152; j += 256) {
        int rr = j >> 7, c = j & 127;          // rr==8 -> X1
        int u = c >> 6, cc = c & 63;
        int o = (rr < 8) ? (64 + rr * 64 + cc) : cc;
        S2P[(size_t)blockIdx.x * 1152 + j] = red[(u * 2) * 576 + o] + red[(u * 2 + 1) * 576 + o];
    }
}

// ---------------- reduce S2P[NB][1152] -> S2X1[1152] (atomic finish, 8 stripes) ----------------
__global__ void s2red_k(const float* __restrict__ S2P, float* __restrict__ S2X1) {
    int cb = blockIdx.x % 5, stripe = blockIdx.x / 5;
    int c = cb * 256 + threadIdx.x;
    if (c >= 1152) return;
    int b0 = stripe * 196, b1 = min(NB, b0 + 196);
    float s0 = 0.f, s1 = 0.f;
    int b = b0;
    for (; b + 1 < b1; b += 2) {
        s0 += S2P[(size_t)b * 1152 + c];
        s1 += S2P[(size_t)(b + 1) * 1152 + c];
    }
    if (b < b1) s0 += S2P[(size_t)b * 1152 + c];
    atomicAdd(&S2X1[c], s0 + s1);
}

// ---------------- final: out = (S2.W2 + X1.root2)/N + b2  (1024 thr, 8-way split) ----------------
__global__ __launch_bounds__(1024) void final_k(
    const float* __restrict__ S2X1, const float* __restrict__ W2,
    const float* __restrict__ root2, const float* __restrict__ b2, float* __restrict__ out)
{
    __shared__ float red[1024];
    const int o = threadIdx.x & 127, c = threadIdx.x >> 7;  // 8 chunks of 144 terms
    float s = 0.f;
    for (int j = c * 144; j < (c + 1) * 144; ++j) {
        float v = S2X1[j];
        float w = (j < 1024) ? W2[(size_t)j * DIM + o] : root2[(size_t)(j - 1024) * DIM + o];
        s += v * w;
    }
    red[threadIdx.x] = s;
    __syncthreads();
    if (c == 0) {
        float tot = 0.f;
#pragma unroll
        for (int k = 0; k < 8; ++k) tot += red[o + 128 * k];
        out[o] = tot * (1.0f / NN) + b2[o];
    }
}

extern "C" void kernel_launch(void* const* d_in, const int* in_sizes, int n_in,
                              void* d_out, int out_size, void* d_ws, size_t ws_size,
                              hipStream_t stream)
{
    const int*   h     = (const int*)d_in[0];
    const int*   r     = (const int*)d_in[1];
    const int*   t     = (const int*)d_in[2];
    const float* x_emb = (const float*)d_in[3];
    const float* W1    = (const float*)d_in[4];
    const float* root1 = (const float*)d_in[5];
    const float* b1    = (const float*)d_in[6];
    const float* W2    = (const float*)d_in[7];
    const float* root2 = (const float*)d_in[8];
    const float* b2    = (const float*)d_in[9];

    float* ws   = (float*)d_ws;
    float* cnt  = ws + OFF_CNT;     // int counts then inv floats in place
    float* wsum = ws + OFF_WSUM;
    float* S2   = ws + OFF_S2;      // 1024 S2 + 128 X1 contiguous
    int*   offs = (int*)(ws + OFF_OFFS);
    int*   part = (int*)(ws + OFF_PART);
    int*   eh   = (int*)(ws + OFF_EH);
    __bf16* xb  = (__bf16*)(ws + OFF_XB);
    __bf16* wf  = (__bf16*)(ws + OFF_WF);
    float* S2P  = ws + OFF_S2P;

    // zero counts + wsum + S2X1 (ws re-poisoned to 0xAA before every timed launch)
    hipMemsetAsync(ws, 0, (size_t)801152 * sizeof(float), stream);

    // merged cast + weight-frag + count
    prep_k<<<1600, 256, 0, stream>>>(x_emb, xb, W1, root1, wf, r, t, (int*)cnt);

    // 3-pass exclusive scan: cnt -> offs (+inv in place)
    scanA_k<<<391, 256, 0, stream>>>((const int*)cnt, cnt, offs, part);
    scanB_k<<<1, 512, 0, stream>>>(part);
    scanC_k<<<391, 256, 0, stream>>>(offs, part);

    // merged fill + wsum single edge pass (4 edges/thread)
    fillw_k<<<782, 256, 0, stream>>>(h, r, t, offs, eh, cnt, wsum);

    // fused layer 1 + layer-2 partials, edge-balanced streaming gather
    rgcn_fused_k<<<NB, 256, 0, stream>>>(offs, eh, cnt, xb, wf, b1, wsum, S2P);

    s2red_k<<<40, 256, 0, stream>>>(S2P, S2);
    final_k<<<1, 1024, 0, stream>>>(S2, W2, root2, b2, (float*)d_out);
}

// Round 16
// 342.207 us; speedup vs baseline: 2.1456x; 2.1456x over previous
//
#include <hip/hip_runtime.h>
#include <hip/hip_bf16.h>

#define NN 50000
#define NR 8
#define DIM 128
#define NE 800000
#define TM 32     // targets per block
#define PAD 136   // A-tile row stride in bf16 (128 + 8): 2-way LDS conflicts only (free)
#define CAP 1024  // per-block bucket capacity (mean 512, Poisson -> overflow prob ~0; guarded)
#define NB 1563   // ceil(NN/TM)

using floatx4 = __attribute__((ext_vector_type(4))) float;
using bf16x8  = __attribute__((ext_vector_type(8))) __bf16;

// ---------------- workspace layout (in floats) ----------------
// zeroed region: [0, 826160) = cnt + wsum + S2X1 + blkcnt
#define OFF_CNT   0u         // 400000: int counts, seg = t*8+r
#define OFF_WSUM  400000u    // 400000: wsum[r*NN+h] fp32 atomic accum
#define OFF_S2    800000u    // 1152: S2[1024] + X1[128]
#define OFF_BCNT  801152u    // 1563*16 ints: per-block bucket counters (64B stride)
#define OFF_BBUF  826160u    // 1563*1024 ints: per-block edge buckets, pk = (lseg<<17)|head
#define OFF_XB    2426672u   // 6.4M bf16: x_emb in bf16 (16B aligned)
#define OFF_WF    5626672u   // 9*2048*8 bf16: weights in MFMA frag order
#define OFF_S2P   5700400u   // NB*1152: per-block S2/X1 partials
// total 7,500,976 floats = 30.0 MB

// ---------------- merged prep: bf16 cast + weight frags + cnt atomics + bucket assign ----------------
__global__ __launch_bounds__(256) void prep_k(
    const float* __restrict__ x, __bf16* __restrict__ xb,
    const float* __restrict__ W1, const float* __restrict__ root1, __bf16* __restrict__ wf,
    const int* __restrict__ h, const int* __restrict__ r, const int* __restrict__ t,
    int* __restrict__ cnt, int* __restrict__ blkcnt, int* __restrict__ blkbuf)
{
    const int gid = blockIdx.x * 256 + threadIdx.x;
    const int nthr = gridDim.x * 256;

    if (gid < 9 * 2048) {
        int mat = gid >> 11, idx = gid & 2047;
        const float* B = (mat < 8) ? (W1 + (size_t)mat * DIM * DIM) : root1;
        int lt = idx & 63, fid = idx >> 6;
        int s = fid >> 3, nt = fid & 7;
        int n = nt * 16 + (lt & 15);
        int kb = s * 32 + (lt >> 4) * 8;
        bf16x8 v;
#pragma unroll
        for (int j = 0; j < 8; ++j) v[j] = (__bf16)B[(kb + j) * DIM + n];
        *reinterpret_cast<bf16x8*>(wf + ((size_t)mat * 2048 + idx) * 8) = v;
    }
    for (int i = gid; i < NN * DIM / 4; i += nthr) {
        int base = i * 4;
        float4 v = *reinterpret_cast<const float4*>(x + base);
        __bf16 o[4] = {(__bf16)v.x, (__bf16)v.y, (__bf16)v.z, (__bf16)v.w};
        *reinterpret_cast<uint2*>(xb + base) = *reinterpret_cast<uint2*>(o);
    }
    // edge loop: cnt atomic + bucket append (shares the h/r/t loads)
    for (int i = gid; i < NE / 4; i += nthr) {
        int base = i * 4;
        int4 hv = *reinterpret_cast<const int4*>(h + base);
        int4 rv = *reinterpret_cast<const int4*>(r + base);
        int4 tv = *reinterpret_cast<const int4*>(t + base);
#pragma unroll
        for (int j = 0; j < 4; ++j) {
            int te = (j == 0) ? tv.x : (j == 1) ? tv.y : (j == 2) ? tv.z : tv.w;
            int re = (j == 0) ? rv.x : (j == 1) ? rv.y : (j == 2) ? rv.z : rv.w;
            int he = (j == 0) ? hv.x : (j == 1) ? hv.y : (j == 2) ? hv.z : hv.w;
            atomicAdd(&cnt[te * NR + re], 1);
            int blk = te >> 5;
            int pos = atomicAdd(&blkcnt[blk * 16], 1);
            if (pos < CAP) blkbuf[blk * CAP + pos] = ((((te & 31) * NR) + re) << 17) | he;
        }
    }
}

// ---------------- wsum: 800k fire-and-forget float atomics; inv derived from cnt (no scan!) ----------------
__global__ void wsum_k(const int* __restrict__ h, const int* __restrict__ r, const int* __restrict__ t,
                       const int* __restrict__ cnt, float* __restrict__ wsum) {
    int base = (blockIdx.x * 256 + threadIdx.x) * 4;
    if (base + 3 < NE) {
        int4 hv = *reinterpret_cast<const int4*>(h + base);
        int4 rv = *reinterpret_cast<const int4*>(r + base);
        int4 tv = *reinterpret_cast<const int4*>(t + base);
        int c0 = cnt[tv.x * NR + rv.x], c1 = cnt[tv.y * NR + rv.y];
        int c2 = cnt[tv.z * NR + rv.z], c3 = cnt[tv.w * NR + rv.w];
        atomicAdd(&wsum[rv.x * NN + hv.x], 1.0f / (float)(c0 > 1 ? c0 : 1));
        atomicAdd(&wsum[rv.y * NN + hv.y], 1.0f / (float)(c1 > 1 ? c1 : 1));
        atomicAdd(&wsum[rv.z * NN + hv.z], 1.0f / (float)(c2 > 1 ? c2 : 1));
        atomicAdd(&wsum[rv.w * NN + hv.w], 1.0f / (float)(c3 > 1 ? c3 : 1));
    } else {
        for (int e = base; e < NE; ++e) {
            int c = cnt[t[e] * NR + r[e]];
            atomicAdd(&wsum[r[e] * NN + h[e]], 1.0f / (float)(c > 1 ? c : 1));
        }
    }
}

// ---------------- fused layer 1 + layer-2 partials: local CSR + R14 depth-2 walk ----------------
// Local CSR built from the block's bucket (LDS int atomics = native ds_add, R9-proven);
// walk core is R14's exact depth-2 pipeline reading pkd from LDS. (256,4): the only
// config this compiler compiles without crushing VGPRs below need (R12/R13 evidence).
__global__ __launch_bounds__(256, 4) void rgcn_fused_k(
    const int* __restrict__ blkcnt, const int* __restrict__ blkbuf,
    const __bf16* __restrict__ xb, const __bf16* __restrict__ wf,
    const float* __restrict__ b1, const float* __restrict__ wsum,
    float* __restrict__ S2P)
{
    __shared__ __attribute__((aligned(16))) __bf16 Atile[2][TM * PAD];  // 17.4 KB (scan temp + red reuse)
    __shared__ int   loffs[TM * NR + 1];
    __shared__ int   lcnt[TM * NR];
    __shared__ int   cursor[TM * NR];
    __shared__ float invl[TM * NR];
    __shared__ float wsl[NR][TM];
    __shared__ int   pkd[CAP];          // heads, sorted by local segment
    const int tid = threadIdx.x;
    const int wave = tid >> 6, lane = tid & 63, quad = lane >> 4;
    const int slot = tid >> 4, sl = tid & 15;   // 16 gather slots x 16 lanes
    const int tbase = blockIdx.x * TM;

    // ---- local CSR build ----
    int n = blkcnt[blockIdx.x * 16];
    if (n > CAP) n = CAP;
    const int* gbuf = blkbuf + (size_t)blockIdx.x * CAP;
    lcnt[tid] = 0;
    __syncthreads();
    int pk0 = -1, pk1 = -1, pk2 = -1, pk3 = -1;
    if (tid < n)       { pk0 = gbuf[tid];       atomicAdd(&lcnt[pk0 >> 17], 1); }
    if (tid + 256 < n) { pk1 = gbuf[tid + 256]; atomicAdd(&lcnt[pk1 >> 17], 1); }
    if (tid + 512 < n) { pk2 = gbuf[tid + 512]; atomicAdd(&lcnt[pk2 >> 17], 1); }
    if (tid + 768 < n) { pk3 = gbuf[tid + 768]; atomicAdd(&lcnt[pk3 >> 17], 1); }
    __syncthreads();
    int v = lcnt[tid];
    int* ss = reinterpret_cast<int*>(&Atile[0][0]);
    ss[tid] = v;
    __syncthreads();
#pragma unroll
    for (int off = 1; off < 256; off <<= 1) {
        int val = (tid >= off) ? ss[tid - off] : 0;
        __syncthreads();
        if (tid >= off) ss[tid] += val;
        __syncthreads();
    }
    loffs[tid + 1] = ss[tid];            // inclusive
    if (tid == 0) loffs[0] = 0;
    cursor[tid] = ss[tid] - v;           // exclusive
    invl[tid] = 1.0f / (float)(v > 1 ? v : 1);
    if (tid < NR * TM) {                 // (always true; kept for clarity)
        int rr = tid >> 5, nn = tbase + (tid & 31);
        wsl[rr][tid & 31] = (nn < NN) ? wsum[rr * NN + nn] : 0.f;
    }
    __syncthreads();
    if (pk0 >= 0) { int p = atomicAdd(&cursor[pk0 >> 17], 1); pkd[p] = pk0 & 0x1FFFF; }
    if (pk1 >= 0) { int p = atomicAdd(&cursor[pk1 >> 17], 1); pkd[p] = pk1 & 0x1FFFF; }
    if (pk2 >= 0) { int p = atomicAdd(&cursor[pk2 >> 17], 1); pkd[p] = pk2 & 0x1FFFF; }
    if (pk3 >= 0) { int p = atomicAdd(&cursor[pk3 >> 17], 1); pkd[p] = pk3 & 0x1FFFF; }
    __syncthreads();

    floatx4 C[4];
#pragma unroll
    for (int i = 0; i < 4; ++i) C[i] = (floatx4)0.f;
    const int arow = (wave & 1) * 16 + (lane & 15);   // wave row-strip
    const int ntg0 = (wave >> 1) * 4;                 // wave col-strip (4 nt each)

    // ---- 4 term-pairs: 4 depth-2-pipelined walks (2 rows x 2 terms), 2 A-tiles (R14 exact) ----
    for (int tp = 0; tp < 4; ++tp) {
        int st[4], ln[4];
        float a[4][8];
#pragma unroll
        for (int q = 0; q < 4; ++q) {
            int j = (slot + (q >> 1) * 16) * 8 + tp * 2 + (q & 1);
            st[q] = loffs[j];
            ln[q] = loffs[j + 1] - loffs[j];
#pragma unroll
            for (int k = 0; k < 8; ++k) a[q][k] = 0.f;
        }
        int mx = max(max(ln[0], ln[1]), max(ln[2], ln[3]));
        if (mx > 0) {
            bf16x8 ycur[4];
#pragma unroll
            for (int q = 0; q < 4; ++q) {
                if (0 < ln[q]) {
                    int he = pkd[st[q]];
                    ycur[q] = *reinterpret_cast<const bf16x8*>(xb + (size_t)he * DIM + sl * 8);
                }
            }
            for (int p = 0; p < mx; ++p) {
                bf16x8 ynext[4];
#pragma unroll
                for (int q = 0; q < 4; ++q) {
                    if (p + 1 < ln[q]) {
                        int he = pkd[st[q] + p + 1];
                        ynext[q] = *reinterpret_cast<const bf16x8*>(xb + (size_t)he * DIM + sl * 8);
                    }
                }
#pragma unroll
                for (int q = 0; q < 4; ++q) {
                    if (p < ln[q]) {
#pragma unroll
                        for (int k = 0; k < 8; ++k) a[q][k] += (float)ycur[q][k];
                    }
                }
#pragma unroll
                for (int q = 0; q < 4; ++q) ycur[q] = ynext[q];
            }
        }
#pragma unroll
        for (int q = 0; q < 4; ++q) {
            int trow = slot + (q >> 1) * 16;
            float sc = invl[trow * 8 + tp * 2 + (q & 1)];
            bf16x8 out;
#pragma unroll
            for (int k = 0; k < 8; ++k) out[k] = (__bf16)(a[q][k] * sc);
            *reinterpret_cast<bf16x8*>(&Atile[q & 1][trow * PAD + sl * 8]) = out;
        }
        __syncthreads();
#pragma unroll
        for (int u = 0; u < 2; ++u) {
            const __bf16* wterm = wf + (size_t)(tp * 2 + u) * 2048 * 8;
#pragma unroll
            for (int s = 0; s < 4; ++s) {
                bf16x8 af = *reinterpret_cast<const bf16x8*>(&Atile[u][arow * PAD + s * 32 + quad * 8]);
#pragma unroll
                for (int nt = 0; nt < 4; ++nt) {
                    bf16x8 bf = *reinterpret_cast<const bf16x8*>(
                        wterm + (size_t)((s * 8 + ntg0 + nt) * 64 + lane) * 8);
                    C[nt] = __builtin_amdgcn_mfma_f32_16x16x32_bf16(af, bf, C[nt], 0, 0, 0);
                }
            }
        }
        __syncthreads();
    }

    // ---- root term: A row = xb[t] ----
#pragma unroll
    for (int i = 0; i < 2; ++i) {
        int trow = slot + i * 16;
        int t = tbase + trow;
        bf16x8 out;
        if (t < NN) {
            out = *reinterpret_cast<const bf16x8*>(xb + (size_t)t * DIM + sl * 8);
        } else {
#pragma unroll
            for (int j = 0; j < 8; ++j) out[j] = (__bf16)0.f;
        }
        *reinterpret_cast<bf16x8*>(&Atile[0][trow * PAD + sl * 8]) = out;
    }
    __syncthreads();
    {
        const __bf16* wterm = wf + (size_t)8 * 2048 * 8;
#pragma unroll
        for (int s = 0; s < 4; ++s) {
            bf16x8 af = *reinterpret_cast<const bf16x8*>(&Atile[0][arow * PAD + s * 32 + quad * 8]);
#pragma unroll
            for (int nt = 0; nt < 4; ++nt) {
                bf16x8 bf = *reinterpret_cast<const bf16x8*>(
                    wterm + (size_t)((s * 8 + ntg0 + nt) * 64 + lane) * 8);
                C[nt] = __builtin_amdgcn_mfma_f32_16x16x32_bf16(af, bf, C[nt], 0, 0, 0);
            }
        }
    }
    __syncthreads();   // Atile dead -> reuse as reduction scratch

    // ---- epilogue: bias + relu in-register, fused S2/X1 block partials (R14 exact) ----
    float* red = reinterpret_cast<float*>(&Atile[0][0]);   // [4][576] = 9.2 KB
    const int rowl0 = (wave & 1) * 16 + quad * 4;
    const int colc = lane & 15;
#pragma unroll
    for (int nt = 0; nt < 4; ++nt) {
        float badd = b1[ntg0 * 16 + nt * 16 + colc];
#pragma unroll
        for (int i = 0; i < 4; ++i) C[nt][i] = fmaxf(C[nt][i] + badd, 0.f);
    }
    float rmask[4];
#pragma unroll
    for (int i = 0; i < 4; ++i) rmask[i] = (tbase + rowl0 + i < NN) ? 1.f : 0.f;
#pragma unroll
    for (int nt = 0; nt < 4; ++nt) {
        float p = rmask[0] * C[nt][0] + rmask[1] * C[nt][1] + rmask[2] * C[nt][2] + rmask[3] * C[nt][3];
        p += __shfl_xor(p, 16);
        p += __shfl_xor(p, 32);
        if (quad == 0) red[wave * 576 + nt * 16 + colc] = p;
    }
#pragma unroll
    for (int rr = 0; rr < NR; ++rr) {
        float w0 = wsl[rr][rowl0], w1 = wsl[rr][rowl0 + 1];
        float w2 = wsl[rr][rowl0 + 2], w3 = wsl[rr][rowl0 + 3];
#pragma unroll
        for (int nt = 0; nt < 4; ++nt) {
            float p = w0 * C[nt][0] + w1 * C[nt][1] + w2 * C[nt][2] + w3 * C[nt][3];
            p += __shfl_xor(p, 16);
            p += __shfl_xor(p, 32);
            if (quad == 0) red[wave * 576 + 64 + rr * 64 + nt * 16 + colc] = p;
        }
    }
    __syncthreads();
    for (int j = tid; j < 1152; j += 256) {
        int rr = j >> 7, c = j & 127;          // rr==8 -> X1
        int u = c >> 6, cc = c & 63;
        int o = (rr < 8) ? (64 + rr * 64 + cc) : cc;
        S2P[(size_t)blockIdx.x * 1152 + j] = red[(u * 2) * 576 + o] + red[(u * 2 + 1) * 576 + o];
    }
}

// ---------------- reduce S2P[NB][1152] -> S2X1[1152] (atomic finish, 8 stripes) ----------------
__global__ void s2red_k(const float* __restrict__ S2P, float* __restrict__ S2X1) {
    int cb = blockIdx.x % 5, stripe = blockIdx.x / 5;
    int c = cb * 256 + threadIdx.x;
    if (c >= 1152) return;
    int b0 = stripe * 196, b1 = min(NB, b0 + 196);
    float s0 = 0.f, s1 = 0.f;
    int b = b0;
    for (; b + 1 < b1; b += 2) {
        s0 += S2P[(size_t)b * 1152 + c];
        s1 += S2P[(size_t)(b + 1) * 1152 + c];
    }
    if (b < b1) s0 += S2P[(size_t)b * 1152 + c];
    atomicAdd(&S2X1[c], s0 + s1);
}

// ---------------- final: out = (S2.W2 + X1.root2)/N + b2  (1024 thr, 8-way split) ----------------
__global__ __launch_bounds__(1024) void final_k(
    const float* __restrict__ S2X1, const float* __restrict__ W2,
    const float* __restrict__ root2, const float* __restrict__ b2, float* __restrict__ out)
{
    __shared__ float red[1024];
    const int o = threadIdx.x & 127, c = threadIdx.x >> 7;  // 8 chunks of 144 terms
    float s = 0.f;
    for (int j = c * 144; j < (c + 1) * 144; ++j) {
        float v = S2X1[j];
        float w = (j < 1024) ? W2[(size_t)j * DIM + o] : root2[(size_t)(j - 1024) * DIM + o];
        s += v * w;
    }
    red[threadIdx.x] = s;
    __syncthreads();
    if (c == 0) {
        float tot = 0.f;
#pragma unroll
        for (int k = 0; k < 8; ++k) tot += red[o + 128 * k];
        out[o] = tot * (1.0f / NN) + b2[o];
    }
}

extern "C" void kernel_launch(void* const* d_in, const int* in_sizes, int n_in,
                              void* d_out, int out_size, void* d_ws, size_t ws_size,
                              hipStream_t stream)
{
    const int*   h     = (const int*)d_in[0];
    const int*   r     = (const int*)d_in[1];
    const int*   t     = (const int*)d_in[2];
    const float* x_emb = (const float*)d_in[3];
    const float* W1    = (const float*)d_in[4];
    const float* root1 = (const float*)d_in[5];
    const float* b1    = (const float*)d_in[6];
    const float* W2    = (const float*)d_in[7];
    const float* root2 = (const float*)d_in[8];
    const float* b2    = (const float*)d_in[9];

    float* ws     = (float*)d_ws;
    int*   cnt    = (int*)(ws + OFF_CNT);
    float* wsum   = ws + OFF_WSUM;
    float* S2     = ws + OFF_S2;      // 1024 S2 + 128 X1 contiguous
    int*   blkcnt = (int*)(ws + OFF_BCNT);
    int*   blkbuf = (int*)(ws + OFF_BBUF);
    __bf16* xb    = (__bf16*)(ws + OFF_XB);
    __bf16* wf    = (__bf16*)(ws + OFF_WF);
    float* S2P    = ws + OFF_S2P;

    // zero cnt + wsum + S2X1 + blkcnt (ws re-poisoned to 0xAA before every timed launch)
    hipMemsetAsync(ws, 0, (size_t)826160 * sizeof(float), stream);

    // merged cast + weight-frag + count + bucket-assign (one edge pass)
    prep_k<<<1600, 256, 0, stream>>>(x_emb, xb, W1, root1, wf, h, r, t, cnt, blkcnt, blkbuf);

    // wsum: inv derived from cnt directly (no scan, no CSR)
    wsum_k<<<782, 256, 0, stream>>>(h, r, t, cnt, wsum);

    // fused layer 1 + layer-2 partials: local CSR + depth-2 walk
    rgcn_fused_k<<<NB, 256, 0, stream>>>(blkcnt, blkbuf, xb, wf, b1, wsum, S2P);

    s2red_k<<<40, 256, 0, stream>>>(S2P, S2);
    final_k<<<1, 1024, 0, stream>>>(S2, W2, root2, b2, (float*)d_out);
}